// Round 13
// baseline (556.945 us; speedup 1.0000x reference)
//
#include <hip/hip_runtime.h>
#include <stdint.h>

typedef unsigned short u16;
typedef __bf16 bf16x8 __attribute__((ext_vector_type(8)));
typedef float f32x4 __attribute__((ext_vector_type(4)));
typedef unsigned short u16x8 __attribute__((ext_vector_type(8)));
typedef unsigned short u16x4 __attribute__((ext_vector_type(4)));

__device__ __forceinline__ float b2f(u16 b) {
    return __uint_as_float(((unsigned)b) << 16);
}
__device__ __forceinline__ u16 f2b(float f) {
    unsigned u = __float_as_uint(f);
    unsigned r = (u + 0x7fffu + ((u >> 16) & 1u)) >> 16;  // RNE
    return (u16)r;
}

#define GLDS16(g, l) __builtin_amdgcn_global_load_lds(                        \
    (const __attribute__((address_space(1))) void*)(g),                       \
    (__attribute__((address_space(3))) void*)(l), 16, 0, 0)

// ---------------------------------------------------------------------------
// g16 = r8's g11 body (best measured: 530.7 us total), minus setprio (m190:
// negative on lockstep GEMM schedules), plus OUT_MODE 3 (fused QKV epilogue).
// 256x256 tile, 8 waves (2M x 4N), per-wave 128x64, reg-pipelined 1 step
// ahead, counted vmcnt CKPT(2), chunk-XOR LDS swizzle (0-conflict, r8).
// OUT_MODE: 0 = bf16 [.,N], 1 = f32 [.,N], 2 = bf16 V^T scatter,
//           3 = QKV split: Cout=Qb; Kb=Qb+2^24; Vt=Qb+2^25; tile's N-range
//               selects dst via sel = n0>>10 (ranges are 1024-aligned).
// ---------------------------------------------------------------------------
template<int HAS_BIAS, int RELU, int HAS_RES, int OUT_MODE>
__device__ __forceinline__ void gemm16_body(
    const u16* __restrict__ A, const u16* __restrict__ Bt,
    const float* __restrict__ bias, const float* __restrict__ bias2,
    const float* __restrict__ bias3, const float* __restrict__ res,
    void* __restrict__ Cout, int N, int K,
    long sA, long sB, long sC, long sR, float scale)
{
    __shared__ u16 smem[65536];   // 128 KiB: A [buf][kk] 16KB x4, then B x4

    const long nwg = (long)gridDim.x * gridDim.y * gridDim.z;
    long gid = ((long)blockIdx.z * gridDim.y + blockIdx.y) * gridDim.x + blockIdx.x;
    long logical = (nwg % 8 == 0) ? (gid & 7) * (nwg >> 3) + (gid >> 3) : gid;
    const int bx = (int)(logical % gridDim.x);
    long tmp = logical / gridDim.x;
    const int by = (int)(tmp % gridDim.y);
    const int bz = (int)(tmp / gridDim.y);

    A  += (long)bz * sA;
    Bt += (long)bz * sB;

    const int tid  = threadIdx.x;
    const int lane = tid & 63, wid = tid >> 6;
    const int wm   = wid >> 2, wn = wid & 3;
    const int lr   = lane & 15, lk = lane >> 4;
    const long m0  = (long)by * 256;
    const long n0  = (long)bx * 256;
    const int  NT  = K >> 6;

    const int sch = ((tid & 3) ^ ((tid >> 3) & 3)) * 8;
    const u16* gA0 = A  + (m0 + (tid >> 2)) * (long)K + sch;
    const u16* gB0 = Bt + (n0 + (tid >> 2)) * (long)K + sch;
    const u16* gA1 = gA0 + 128L * K;
    const u16* gB1 = gB0 + 128L * K;
    const int wdst = (tid & ~63) * 8;

#define STA(bufn, kk, kof) do {                                               \
    GLDS16(gA0 + (kof) + (kk) * 32, &smem[(bufn)*16384 + (kk)*8192 + wdst]);  \
    GLDS16(gA1 + (kof) + (kk) * 32, &smem[(bufn)*16384 + (kk)*8192 + wdst + 4096]); } while (0)
#define STB(bufn, kk, kof) do {                                               \
    GLDS16(gB0 + (kof) + (kk) * 32, &smem[32768 + (bufn)*16384 + (kk)*8192 + wdst]); \
    GLDS16(gB1 + (kof) + (kk) * 32, &smem[32768 + (bufn)*16384 + (kk)*8192 + wdst + 4096]); } while (0)

    const int lkA   = lk ^ ((lr >> 1) & 3);
    const int raOff = (wm * 128 + lr) * 32 + lkA * 8;
    const int rbOff = (wn * 64  + lr) * 32 + lkA * 8;

#define DSA(dst, BUF, kk, ih) do { _Pragma("unroll")                          \
    for (int i = 0; i < 4; ++i)                                               \
        dst[i] = *(const bf16x8*)&smem[(BUF)*16384 + (kk)*8192 + raOff + ((ih)*4 + i)*512]; } while (0)
#define DSB(dst, BUF, kk) do { _Pragma("unroll")                              \
    for (int j = 0; j < 4; ++j)                                               \
        dst[j] = *(const bf16x8*)&smem[32768 + (BUF)*16384 + (kk)*8192 + rbOff + j*512]; } while (0)

#define LGK(n) do { asm volatile("s_waitcnt lgkmcnt(" #n ")" ::: "memory");   \
                    __builtin_amdgcn_sched_barrier(0); } while (0)
#define CKPT(n) do { asm volatile("s_waitcnt vmcnt(" #n ")" ::: "memory");    \
    __builtin_amdgcn_s_barrier(); __builtin_amdgcn_sched_barrier(0); } while (0)

#define MFM(IH, A_, B_) do { _Pragma("unroll")                                \
    for (int i = 0; i < 4; ++i) _Pragma("unroll")                             \
        for (int j = 0; j < 4; ++j)                                           \
            acc[(IH)*4 + i][j] = __builtin_amdgcn_mfma_f32_16x16x32_bf16(     \
                A_[i], B_[j], acc[(IH)*4 + i][j], 0, 0, 0);                   \
} while (0)

#define TILE_MAIN(BUF, kof) do {                                              \
    DSA(aY, BUF, 0, 1);                 STA((BUF)^1, 0, kof);                 \
    LGK(4);  MFM(0, aX, bX);                                                  \
    CKPT(2);                                                                  \
    DSA(aX, BUF, 1, 0);  DSB(bY, BUF, 1);  STB((BUF)^1, 0, kof);              \
    LGK(8);  MFM(1, aY, bX);                                                  \
    DSA(aY, BUF, 1, 1);                 STA((BUF)^1, 1, kof);                 \
    LGK(4);  MFM(0, aX, bY);                                                  \
    CKPT(2);                                                                  \
    DSA(aX, (BUF)^1, 0, 0);  DSB(bX, (BUF)^1, 0);  STB((BUF)^1, 1, kof);      \
    LGK(8);  MFM(1, aY, bY);                                                  \
} while (0)

#define TILE_LAST(BUF) do {                                                   \
    DSA(aY, BUF, 0, 1);                                                       \
    LGK(4);  MFM(0, aX, bX);                                                  \
    CKPT(0);                                                                  \
    DSA(aX, BUF, 1, 0);  DSB(bY, BUF, 1);                                     \
    LGK(8);  MFM(1, aY, bX);                                                  \
    DSA(aY, BUF, 1, 1);                                                       \
    LGK(4);  MFM(0, aX, bY);                                                  \
    LGK(0);  MFM(1, aY, bY);                                                  \
} while (0)

    f32x4 acc[8][4];
    #pragma unroll
    for (int i = 0; i < 8; ++i)
        #pragma unroll
        for (int j = 0; j < 4; ++j)
            #pragma unroll
            for (int r = 0; r < 4; ++r) acc[i][j][r] = 0.0f;

    bf16x8 aX[4], aY[4], bX[4], bY[4];

    STA(0, 0, 0); STB(0, 0, 0); STA(0, 1, 0); STB(0, 1, 0);
    CKPT(4);
    DSA(aX, 0, 0, 0); DSB(bX, 0, 0);

    #pragma unroll 1
    for (int t = 0; t + 2 < NT; t += 2) {
        TILE_MAIN(0, (long)(t + 1) * 64);
        TILE_MAIN(1, (long)(t + 2) * 64);
    }
    TILE_MAIN(0, (long)(NT - 1) * 64);
    TILE_LAST(1);

    // epilogue: C/D layout col = lane&15, row = (lane>>4)*4 + reg  [m89]
    const long crow0 = m0 + wm * 128;
    const long ccol0 = n0 + wn * 64;
    u16*   Cb = (u16*)Cout   + (long)bz * sC;
    float* Cf = (float*)Cout + (long)bz * sC;
    const float* resz = res + (long)bz * sR;
    // OUT_MODE 3: block-uniform destination select (N-ranges 1024-aligned)
    const int sel = (OUT_MODE == 3) ? (int)(n0 >> 10) : 0;
    const float* bp3 = (OUT_MODE == 3)
        ? (sel == 0 ? bias : (sel == 1 ? bias2 : bias3)) : nullptr;
    u16* qk3 = (OUT_MODE == 3) ? ((u16*)Cout + ((long)sel << 24)) : nullptr;
    u16* vt3 = (OUT_MODE == 3) ? ((u16*)Cout + (2L << 24)) : nullptr;

    #pragma unroll
    for (int i = 0; i < 8; ++i) {
        #pragma unroll
        for (int j = 0; j < 4; ++j) {
            const long col = ccol0 + j * 16 + lr;
            if (OUT_MODE == 3) {
                const long c10 = col & 1023;
                const float bv_ = bp3[c10];
                if (sel < 2) {
                    #pragma unroll
                    for (int r = 0; r < 4; ++r) {
                        const long row = crow0 + i * 16 + lk * 4 + r;
                        qk3[row * 1024 + c10] = f2b(acc[i][j][r] + bv_);
                    }
                } else {
                    const long row0 = crow0 + i * 16 + lk * 4;
                    u16x4 pk;
                    #pragma unroll
                    for (int r = 0; r < 4; ++r) pk[r] = f2b(acc[i][j][r] + bv_);
                    const long b_ = row0 >> 12, s_ = row0 & 4095;
                    *(u16x4*)(vt3 + (b_ << 22) + (c10 << 12) + s_) = pk;
                }
                continue;
            }
            float bv_ = 0.0f;
            if (HAS_BIAS) bv_ = bias[col];
            if (OUT_MODE == 2) {
                const long row0 = crow0 + i * 16 + lk * 4;
                u16x4 pk;
                #pragma unroll
                for (int r = 0; r < 4; ++r) {
                    float v = acc[i][j][r] + bv_;
                    v *= scale;
                    pk[r] = f2b(v);
                }
                const long b_ = row0 >> 12, s_ = row0 & 4095;
                *(u16x4*)((u16*)Cout + (b_ << 22) + (col << 12) + s_) = pk;
            } else {
                #pragma unroll
                for (int r = 0; r < 4; ++r) {
                    const long row = crow0 + i * 16 + lk * 4 + r;
                    float v = acc[i][j][r];
                    if (HAS_BIAS) v += bv_;
                    v *= scale;
                    if (RELU) v = fmaxf(v, 0.0f);
                    if (HAS_RES) v += resz[row * (long)N + col];
                    if (OUT_MODE == 1) Cf[row * (long)N + col] = v;
                    else               Cb[row * (long)N + col] = f2b(v);
                }
            }
        }
    }
#undef STA
#undef STB
#undef DSA
#undef DSB
#undef LGK
#undef CKPT
#undef MFM
#undef TILE_MAIN
#undef TILE_LAST
}

// wrappers (distinct names for rocprof attribution) ---------------------------
__global__ __launch_bounds__(512, 2) void g16_qkv(
    const u16* A, const u16* Bt, const float* bq, const float* bk,
    const float* bv, u16* Qb, int K)
{ gemm16_body<1,0,0,3>(A, Bt, bq, bk, bv, nullptr, Qb, 1024, K, 0,0,0,0, 1.0f); }

__global__ __launch_bounds__(512, 2) void g16_qkt(
    const u16* A, const u16* Bt, u16* C, int N, int K,
    long sA, long sB, long sC, float scale)
{ gemm16_body<0,0,0,0>(A, Bt, nullptr, nullptr, nullptr, nullptr, C, N, K, sA, sB, sC, 0, scale); }

__global__ __launch_bounds__(512, 2) void g16_pv(
    const u16* A, const u16* Bt, const float* res, u16* C, int N, int K,
    long sA, long sB, long sC, long sR)
{ gemm16_body<0,0,1,0>(A, Bt, nullptr, nullptr, nullptr, res, C, N, K, sA, sB, sC, sR, 1.0f); }

__global__ __launch_bounds__(512, 2) void g16_ffn1(
    const u16* A, const u16* Bt, const float* bias, u16* C, int N, int K)
{ gemm16_body<1,1,0,0>(A, Bt, bias, nullptr, nullptr, nullptr, C, N, K, 0,0,0,0, 1.0f); }

__global__ __launch_bounds__(512, 2) void g16_ffn2(
    const u16* A, const u16* Bt, const float* bias, float* C, int N, int K, float scale)
{ gemm16_body<1,0,0,1>(A, Bt, bias, nullptr, nullptr, nullptr, C, N, K, 0,0,0,0, scale); }

// ---------------------------------------------------------------------------
__global__ __launch_bounds__(256) void cvt_f32_bf16(
    const float* __restrict__ in, u16* __restrict__ out, long n)
{
    long i = ((long)blockIdx.x * 256 + threadIdx.x) * 4;
    if (i >= n) return;
    float4 f = *(const float4*)(in + i);
    u16x4 o;
    o[0] = f2b(f.x); o[1] = f2b(f.y); o[2] = f2b(f.z); o[3] = f2b(f.w);
    *(u16x4*)(out + i) = o;
}

// fused 5-way DxD weight transpose+convert: z selects the weight.
__global__ __launch_bounds__(256) void transpose5_to_bf16(
    const float* __restrict__ Wq, const float* __restrict__ Wk,
    const float* __restrict__ Wv, const float* __restrict__ W1,
    const float* __restrict__ W2, u16* __restrict__ out, int Dm)
{
    const int z = blockIdx.z;
    const float* in = (z == 0) ? Wq : (z == 1) ? Wk : (z == 2) ? Wv
                    : (z == 3) ? W1 : W2;
    u16* o = out + (long)z * Dm * Dm;
    __shared__ float tile[32][33];
    const int bx = blockIdx.x * 32;
    const int by = blockIdx.y * 32;
    const int tx = threadIdx.x, ty = threadIdx.y;
    #pragma unroll
    for (int i = 0; i < 32; i += 8)
        tile[ty + i][tx] = in[(long)(by + ty + i) * Dm + bx + tx];
    __syncthreads();
    #pragma unroll
    for (int i = 0; i < 32; i += 8)
        o[(long)(bx + ty + i) * Dm + by + tx] = f2b(tile[tx][ty + i]);
}

// in-place row softmax over n=4096 bf16 elements; one block per row.
__global__ __launch_bounds__(256) void softmax_rows(u16* __restrict__ P, int n)
{
    const int t = threadIdx.x;
    const int lane = t & 63, w = t >> 6;
    u16* row = P + (long)blockIdx.x * n;
    u16x8 a = *(const u16x8*)(row + t * 16);
    u16x8 b = *(const u16x8*)(row + t * 16 + 8);
    float v[16];
    #pragma unroll
    for (int i = 0; i < 8; ++i) { v[i] = b2f(a[i]); v[8 + i] = b2f(b[i]); }

    float mx = v[0];
    #pragma unroll
    for (int i = 1; i < 16; ++i) mx = fmaxf(mx, v[i]);
    #pragma unroll
    for (int o = 32; o > 0; o >>= 1) mx = fmaxf(mx, __shfl_xor(mx, o));
    __shared__ float red[8];
    if (lane == 0) red[w] = mx;
    __syncthreads();
    mx = fmaxf(fmaxf(red[0], red[1]), fmaxf(red[2], red[3]));

    float s = 0.0f;
    #pragma unroll
    for (int i = 0; i < 16; ++i) { v[i] = __expf(v[i] - mx); s += v[i]; }
    #pragma unroll
    for (int o = 32; o > 0; o >>= 1) s += __shfl_xor(s, o);
    if (lane == 0) red[4 + w] = s;
    __syncthreads();
    s = red[4] + red[5] + red[6] + red[7];
    const float inv = 1.0f / s;

    #pragma unroll
    for (int i = 0; i < 8; ++i) { a[i] = f2b(v[i] * inv); b[i] = f2b(v[8 + i] * inv); }
    *(u16x8*)(row + t * 16)     = a;
    *(u16x8*)(row + t * 16 + 8) = b;
}

// ---------------------------------------------------------------------------
extern "C" void kernel_launch(void* const* d_in, const int* in_sizes, int n_in,
                              void* d_out, int out_size, void* d_ws, size_t ws_size,
                              hipStream_t stream)
{
    (void)in_sizes; (void)n_in; (void)out_size;
    const float* x  = (const float*)d_in[0];
    const float* Wq = (const float*)d_in[1];
    const float* bq = (const float*)d_in[2];
    const float* Wk = (const float*)d_in[3];
    const float* bk = (const float*)d_in[4];
    const float* Wv = (const float*)d_in[5];
    const float* bv = (const float*)d_in[6];
    const float* W1 = (const float*)d_in[7];
    const float* b1 = (const float*)d_in[8];
    const float* W2 = (const float*)d_in[9];
    const float* b2 = (const float*)d_in[10];
    float* out = (float*)d_out;

    const int  B = 4, S = 4096, D = 1024;
    const long SD  = (long)S * D;           // 4 Mi
    const long BSD = (long)B * SD;          // 16 Mi = 1<<24
    const long SS  = (long)S * S;           // 16 Mi

    // score-chunk size BC: P holds BC*SS elems, aliasing xb (dead after proj)
    int BC = 4;
    while (BC > 1 && (size_t)((long)BC * SS + 5L * D * D + 3L * BSD) * 2 > ws_size)
        BC >>= 1;

    // workspace layout (u16 elements).  NOTE: Qb, Kb, Vt are contiguous —
    // the fused QKV epilogue (OUT_MODE 3) relies on Kb = Qb + 2^24 and
    // Vt = Qb + 2^25.
    u16* Pb = (u16*)d_ws;            // [BC, S, S] scores; xb aliases Pb
    u16* xb = Pb;                    // [B*S, D] x bf16 (dead after proj)
    u16* Wt = Pb + (long)BC * SS;    // 5 x [D, D]
    u16* Qb = Wt + 5L * D * D;       // [B*S, D]   (later: h)
    u16* Kb = Qb + BSD;              // [B*S, D]   (later: x_res)
    u16* Vt = Kb + BSD;              // B x [D, S]

    cvt_f32_bf16<<<dim3((unsigned)(BSD / 4 / 256)), 256, 0, stream>>>(x, xb, BSD);

    transpose5_to_bf16<<<dim3(D / 32, D / 32, 5), dim3(32, 8), 0, stream>>>(
        Wq, Wk, Wv, W1, W2, Wt, D);

    // fused QKV: [B*S, D] @ [3D, D]^T -> Qb | Kb | V^T
    g16_qkv<<<dim3(3 * D / 256, (B * S) / 256), 512, 0, stream>>>(
        xb, Wt, bq, bk, bv, Qb, D);
    // xb is dead from here; Pb may overwrite it.

    for (int c = 0; c < B; c += BC) {
        g16_qkt<<<dim3(S/256, S/256, BC), 512, 0, stream>>>(
            Qb + (long)c * SD, Kb + (long)c * SD, Pb, S, D, SD, SD, SS, 0.03125f);
        softmax_rows<<<BC * S, 256, 0, stream>>>(Pb, S);
        g16_pv<<<dim3(D/256, S/256, BC), 512, 0, stream>>>(
            Pb, Vt + (long)c * SD, x + (long)c * SD, Kb + (long)c * SD,
            D, S, SS, SD, SD, SD);
    }

    const dim3 gproj(D / 256, (B * S) / 256);    // (4, 64) = 256 blocks
    // FFN: h = relu(x_res @ W1 + b1) -> Qb;  out = 2*(h @ W2 + b2) fp32
    g16_ffn1<<<gproj, 512, 0, stream>>>(Kb, Wt + 3L*D*D, b1, Qb, D, D);
    g16_ffn2<<<gproj, 512, 0, stream>>>(Qb, Wt + 4L*D*D, b2, out, D, D, 2.0f);
}

// Round 14
// 522.502 us; speedup vs baseline: 1.0659x; 1.0659x over previous
//
#include <hip/hip_runtime.h>
#include <stdint.h>

typedef unsigned short u16;
typedef __bf16 bf16x8 __attribute__((ext_vector_type(8)));
typedef float f32x4 __attribute__((ext_vector_type(4)));
typedef unsigned short u16x8 __attribute__((ext_vector_type(8)));
typedef unsigned short u16x4 __attribute__((ext_vector_type(4)));

__device__ __forceinline__ float b2f(u16 b) {
    return __uint_as_float(((unsigned)b) << 16);
}
__device__ __forceinline__ u16 f2b(float f) {
    unsigned u = __float_as_uint(f);
    unsigned r = (u + 0x7fffu + ((u >> 16) & 1u)) >> 16;  // RNE
    return (u16)r;
}

#define GLDS16(g, l) __builtin_amdgcn_global_load_lds(                        \
    (const __attribute__((address_space(1))) void*)(g),                       \
    (__attribute__((address_space(3))) void*)(l), 16, 0, 0)

// ---------------------------------------------------------------------------
// g17 = g16 with setprio RESTORED (r13 A/B: removing it cost +8% on qkt).
// 256x256 tile, 8 waves (2M x 4N), per-wave 128x64, reg-pipelined 1 step
// ahead, counted vmcnt CKPT(2), chunk-XOR LDS swizzle (0-conflict, r8),
// fused QKV epilogue (OUT_MODE 3).
// OUT_MODE: 0 = bf16 [.,N], 1 = f32 [.,N], 2 = bf16 V^T scatter,
//           3 = QKV split: Cout=Qb; Kb=Qb+2^24; Vt=Qb+2^25; tile's N-range
//               selects dst via sel = n0>>10 (ranges are 1024-aligned).
// ---------------------------------------------------------------------------
template<int HAS_BIAS, int RELU, int HAS_RES, int OUT_MODE>
__device__ __forceinline__ void gemm17_body(
    const u16* __restrict__ A, const u16* __restrict__ Bt,
    const float* __restrict__ bias, const float* __restrict__ bias2,
    const float* __restrict__ bias3, const float* __restrict__ res,
    void* __restrict__ Cout, int N, int K,
    long sA, long sB, long sC, long sR, float scale)
{
    __shared__ u16 smem[65536];   // 128 KiB: A [buf][kk] 16KB x4, then B x4

    const long nwg = (long)gridDim.x * gridDim.y * gridDim.z;
    long gid = ((long)blockIdx.z * gridDim.y + blockIdx.y) * gridDim.x + blockIdx.x;
    long logical = (nwg % 8 == 0) ? (gid & 7) * (nwg >> 3) + (gid >> 3) : gid;
    const int bx = (int)(logical % gridDim.x);
    long tmp = logical / gridDim.x;
    const int by = (int)(tmp % gridDim.y);
    const int bz = (int)(tmp / gridDim.y);

    A  += (long)bz * sA;
    Bt += (long)bz * sB;

    const int tid  = threadIdx.x;
    const int lane = tid & 63, wid = tid >> 6;
    const int wm   = wid >> 2, wn = wid & 3;
    const int lr   = lane & 15, lk = lane >> 4;
    const long m0  = (long)by * 256;
    const long n0  = (long)bx * 256;
    const int  NT  = K >> 6;

    const int sch = ((tid & 3) ^ ((tid >> 3) & 3)) * 8;
    const u16* gA0 = A  + (m0 + (tid >> 2)) * (long)K + sch;
    const u16* gB0 = Bt + (n0 + (tid >> 2)) * (long)K + sch;
    const u16* gA1 = gA0 + 128L * K;
    const u16* gB1 = gB0 + 128L * K;
    const int wdst = (tid & ~63) * 8;

#define STA(bufn, kk, kof) do {                                               \
    GLDS16(gA0 + (kof) + (kk) * 32, &smem[(bufn)*16384 + (kk)*8192 + wdst]);  \
    GLDS16(gA1 + (kof) + (kk) * 32, &smem[(bufn)*16384 + (kk)*8192 + wdst + 4096]); } while (0)
#define STB(bufn, kk, kof) do {                                               \
    GLDS16(gB0 + (kof) + (kk) * 32, &smem[32768 + (bufn)*16384 + (kk)*8192 + wdst]); \
    GLDS16(gB1 + (kof) + (kk) * 32, &smem[32768 + (bufn)*16384 + (kk)*8192 + wdst + 4096]); } while (0)

    const int lkA   = lk ^ ((lr >> 1) & 3);
    const int raOff = (wm * 128 + lr) * 32 + lkA * 8;
    const int rbOff = (wn * 64  + lr) * 32 + lkA * 8;

#define DSA(dst, BUF, kk, ih) do { _Pragma("unroll")                          \
    for (int i = 0; i < 4; ++i)                                               \
        dst[i] = *(const bf16x8*)&smem[(BUF)*16384 + (kk)*8192 + raOff + ((ih)*4 + i)*512]; } while (0)
#define DSB(dst, BUF, kk) do { _Pragma("unroll")                              \
    for (int j = 0; j < 4; ++j)                                               \
        dst[j] = *(const bf16x8*)&smem[32768 + (BUF)*16384 + (kk)*8192 + rbOff + j*512]; } while (0)

#define LGK(n) do { asm volatile("s_waitcnt lgkmcnt(" #n ")" ::: "memory");   \
                    __builtin_amdgcn_sched_barrier(0); } while (0)
#define CKPT(n) do { asm volatile("s_waitcnt vmcnt(" #n ")" ::: "memory");    \
    __builtin_amdgcn_s_barrier(); __builtin_amdgcn_sched_barrier(0); } while (0)

#define MFM(IH, A_, B_) do { __builtin_amdgcn_s_setprio(1); _Pragma("unroll") \
    for (int i = 0; i < 4; ++i) _Pragma("unroll")                             \
        for (int j = 0; j < 4; ++j)                                           \
            acc[(IH)*4 + i][j] = __builtin_amdgcn_mfma_f32_16x16x32_bf16(     \
                A_[i], B_[j], acc[(IH)*4 + i][j], 0, 0, 0);                   \
    __builtin_amdgcn_s_setprio(0); } while (0)

#define TILE_MAIN(BUF, kof) do {                                              \
    DSA(aY, BUF, 0, 1);                 STA((BUF)^1, 0, kof);                 \
    LGK(4);  MFM(0, aX, bX);                                                  \
    CKPT(2);                                                                  \
    DSA(aX, BUF, 1, 0);  DSB(bY, BUF, 1);  STB((BUF)^1, 0, kof);              \
    LGK(8);  MFM(1, aY, bX);                                                  \
    DSA(aY, BUF, 1, 1);                 STA((BUF)^1, 1, kof);                 \
    LGK(4);  MFM(0, aX, bY);                                                  \
    CKPT(2);                                                                  \
    DSA(aX, (BUF)^1, 0, 0);  DSB(bX, (BUF)^1, 0);  STB((BUF)^1, 1, kof);      \
    LGK(8);  MFM(1, aY, bY);                                                  \
} while (0)

#define TILE_LAST(BUF) do {                                                   \
    DSA(aY, BUF, 0, 1);                                                       \
    LGK(4);  MFM(0, aX, bX);                                                  \
    CKPT(0);                                                                  \
    DSA(aX, BUF, 1, 0);  DSB(bY, BUF, 1);                                     \
    LGK(8);  MFM(1, aY, bX);                                                  \
    DSA(aY, BUF, 1, 1);                                                       \
    LGK(4);  MFM(0, aX, bY);                                                  \
    LGK(0);  MFM(1, aY, bY);                                                  \
} while (0)

    f32x4 acc[8][4];
    #pragma unroll
    for (int i = 0; i < 8; ++i)
        #pragma unroll
        for (int j = 0; j < 4; ++j)
            #pragma unroll
            for (int r = 0; r < 4; ++r) acc[i][j][r] = 0.0f;

    bf16x8 aX[4], aY[4], bX[4], bY[4];

    STA(0, 0, 0); STB(0, 0, 0); STA(0, 1, 0); STB(0, 1, 0);
    CKPT(4);
    DSA(aX, 0, 0, 0); DSB(bX, 0, 0);

    #pragma unroll 1
    for (int t = 0; t + 2 < NT; t += 2) {
        TILE_MAIN(0, (long)(t + 1) * 64);
        TILE_MAIN(1, (long)(t + 2) * 64);
    }
    TILE_MAIN(0, (long)(NT - 1) * 64);
    TILE_LAST(1);

    // epilogue: C/D layout col = lane&15, row = (lane>>4)*4 + reg  [m89]
    const long crow0 = m0 + wm * 128;
    const long ccol0 = n0 + wn * 64;
    u16*   Cb = (u16*)Cout   + (long)bz * sC;
    float* Cf = (float*)Cout + (long)bz * sC;
    const float* resz = res + (long)bz * sR;
    const int sel = (OUT_MODE == 3) ? (int)(n0 >> 10) : 0;
    const float* bp3 = (OUT_MODE == 3)
        ? (sel == 0 ? bias : (sel == 1 ? bias2 : bias3)) : nullptr;
    u16* qk3 = (OUT_MODE == 3) ? ((u16*)Cout + ((long)sel << 24)) : nullptr;
    u16* vt3 = (OUT_MODE == 3) ? ((u16*)Cout + (2L << 24)) : nullptr;

    #pragma unroll
    for (int i = 0; i < 8; ++i) {
        #pragma unroll
        for (int j = 0; j < 4; ++j) {
            const long col = ccol0 + j * 16 + lr;
            if (OUT_MODE == 3) {
                const long c10 = col & 1023;
                const float bv_ = bp3[c10];
                if (sel < 2) {
                    #pragma unroll
                    for (int r = 0; r < 4; ++r) {
                        const long row = crow0 + i * 16 + lk * 4 + r;
                        qk3[row * 1024 + c10] = f2b(acc[i][j][r] + bv_);
                    }
                } else {
                    const long row0 = crow0 + i * 16 + lk * 4;
                    u16x4 pk;
                    #pragma unroll
                    for (int r = 0; r < 4; ++r) pk[r] = f2b(acc[i][j][r] + bv_);
                    const long b_ = row0 >> 12, s_ = row0 & 4095;
                    *(u16x4*)(vt3 + (b_ << 22) + (c10 << 12) + s_) = pk;
                }
                continue;
            }
            float bv_ = 0.0f;
            if (HAS_BIAS) bv_ = bias[col];
            if (OUT_MODE == 2) {
                const long row0 = crow0 + i * 16 + lk * 4;
                u16x4 pk;
                #pragma unroll
                for (int r = 0; r < 4; ++r) {
                    float v = acc[i][j][r] + bv_;
                    v *= scale;
                    pk[r] = f2b(v);
                }
                const long b_ = row0 >> 12, s_ = row0 & 4095;
                *(u16x4*)((u16*)Cout + (b_ << 22) + (col << 12) + s_) = pk;
            } else {
                #pragma unroll
                for (int r = 0; r < 4; ++r) {
                    const long row = crow0 + i * 16 + lk * 4 + r;
                    float v = acc[i][j][r];
                    if (HAS_BIAS) v += bv_;
                    v *= scale;
                    if (RELU) v = fmaxf(v, 0.0f);
                    if (HAS_RES) v += resz[row * (long)N + col];
                    if (OUT_MODE == 1) Cf[row * (long)N + col] = v;
                    else               Cb[row * (long)N + col] = f2b(v);
                }
            }
        }
    }
#undef STA
#undef STB
#undef DSA
#undef DSB
#undef LGK
#undef CKPT
#undef MFM
#undef TILE_MAIN
#undef TILE_LAST
}

// wrappers (distinct names for rocprof attribution) ---------------------------
__global__ __launch_bounds__(512, 2) void g17_qkv(
    const u16* A, const u16* Bt, const float* bq, const float* bk,
    const float* bv, u16* Qb, int K)
{ gemm17_body<1,0,0,3>(A, Bt, bq, bk, bv, nullptr, Qb, 1024, K, 0,0,0,0, 1.0f); }

__global__ __launch_bounds__(512, 2) void g17_qkt(
    const u16* A, const u16* Bt, u16* C, int N, int K,
    long sA, long sB, long sC, float scale)
{ gemm17_body<0,0,0,0>(A, Bt, nullptr, nullptr, nullptr, nullptr, C, N, K, sA, sB, sC, 0, scale); }

__global__ __launch_bounds__(512, 2) void g17_pv(
    const u16* A, const u16* Bt, const float* res, u16* C, int N, int K,
    long sA, long sB, long sC, long sR)
{ gemm17_body<0,0,1,0>(A, Bt, nullptr, nullptr, nullptr, res, C, N, K, sA, sB, sC, sR, 1.0f); }

__global__ __launch_bounds__(512, 2) void g17_ffn1(
    const u16* A, const u16* Bt, const float* bias, u16* C, int N, int K)
{ gemm17_body<1,1,0,0>(A, Bt, bias, nullptr, nullptr, nullptr, C, N, K, 0,0,0,0, 1.0f); }

__global__ __launch_bounds__(512, 2) void g17_ffn2(
    const u16* A, const u16* Bt, const float* bias, float* C, int N, int K, float scale)
{ gemm17_body<1,0,0,1>(A, Bt, bias, nullptr, nullptr, nullptr, C, N, K, 0,0,0,0, scale); }

// ---------------------------------------------------------------------------
__global__ __launch_bounds__(256) void cvt_f32_bf16(
    const float* __restrict__ in, u16* __restrict__ out, long n)
{
    long i = ((long)blockIdx.x * 256 + threadIdx.x) * 4;
    if (i >= n) return;
    float4 f = *(const float4*)(in + i);
    u16x4 o;
    o[0] = f2b(f.x); o[1] = f2b(f.y); o[2] = f2b(f.z); o[3] = f2b(f.w);
    *(u16x4*)(out + i) = o;
}

// fused 5-way DxD weight transpose+convert: z selects the weight.
__global__ __launch_bounds__(256) void transpose5_to_bf16(
    const float* __restrict__ Wq, const float* __restrict__ Wk,
    const float* __restrict__ Wv, const float* __restrict__ W1,
    const float* __restrict__ W2, u16* __restrict__ out, int Dm)
{
    const int z = blockIdx.z;
    const float* in = (z == 0) ? Wq : (z == 1) ? Wk : (z == 2) ? Wv
                    : (z == 3) ? W1 : W2;
    u16* o = out + (long)z * Dm * Dm;
    __shared__ float tile[32][33];
    const int bx = blockIdx.x * 32;
    const int by = blockIdx.y * 32;
    const int tx = threadIdx.x, ty = threadIdx.y;
    #pragma unroll
    for (int i = 0; i < 32; i += 8)
        tile[ty + i][tx] = in[(long)(by + ty + i) * Dm + bx + tx];
    __syncthreads();
    #pragma unroll
    for (int i = 0; i < 32; i += 8)
        o[(long)(bx + ty + i) * Dm + by + tx] = f2b(tile[tx][ty + i]);
}

// in-place row softmax over n=4096 bf16 elements; one block per row.
__global__ __launch_bounds__(256) void softmax_rows(u16* __restrict__ P, int n)
{
    const int t = threadIdx.x;
    const int lane = t & 63, w = t >> 6;
    u16* row = P + (long)blockIdx.x * n;
    u16x8 a = *(const u16x8*)(row + t * 16);
    u16x8 b = *(const u16x8*)(row + t * 16 + 8);
    float v[16];
    #pragma unroll
    for (int i = 0; i < 8; ++i) { v[i] = b2f(a[i]); v[8 + i] = b2f(b[i]); }

    float mx = v[0];
    #pragma unroll
    for (int i = 1; i < 16; ++i) mx = fmaxf(mx, v[i]);
    #pragma unroll
    for (int o = 32; o > 0; o >>= 1) mx = fmaxf(mx, __shfl_xor(mx, o));
    __shared__ float red[8];
    if (lane == 0) red[w] = mx;
    __syncthreads();
    mx = fmaxf(fmaxf(red[0], red[1]), fmaxf(red[2], red[3]));

    float s = 0.0f;
    #pragma unroll
    for (int i = 0; i < 16; ++i) { v[i] = __expf(v[i] - mx); s += v[i]; }
    #pragma unroll
    for (int o = 32; o > 0; o >>= 1) s += __shfl_xor(s, o);
    if (lane == 0) red[4 + w] = s;
    __syncthreads();
    s = red[4] + red[5] + red[6] + red[7];
    const float inv = 1.0f / s;

    #pragma unroll
    for (int i = 0; i < 8; ++i) { a[i] = f2b(v[i] * inv); b[i] = f2b(v[8 + i] * inv); }
    *(u16x8*)(row + t * 16)     = a;
    *(u16x8*)(row + t * 16 + 8) = b;
}

// ---------------------------------------------------------------------------
extern "C" void kernel_launch(void* const* d_in, const int* in_sizes, int n_in,
                              void* d_out, int out_size, void* d_ws, size_t ws_size,
                              hipStream_t stream)
{
    (void)in_sizes; (void)n_in; (void)out_size;
    const float* x  = (const float*)d_in[0];
    const float* Wq = (const float*)d_in[1];
    const float* bq = (const float*)d_in[2];
    const float* Wk = (const float*)d_in[3];
    const float* bk = (const float*)d_in[4];
    const float* Wv = (const float*)d_in[5];
    const float* bv = (const float*)d_in[6];
    const float* W1 = (const float*)d_in[7];
    const float* b1 = (const float*)d_in[8];
    const float* W2 = (const float*)d_in[9];
    const float* b2 = (const float*)d_in[10];
    float* out = (float*)d_out;

    const int  B = 4, S = 4096, D = 1024;
    const long SD  = (long)S * D;           // 4 Mi
    const long BSD = (long)B * SD;          // 16 Mi = 1<<24
    const long SS  = (long)S * S;           // 16 Mi

    // score-chunk size BC: P holds BC*SS elems, aliasing xb (dead after proj)
    int BC = 4;
    while (BC > 1 && (size_t)((long)BC * SS + 5L * D * D + 3L * BSD) * 2 > ws_size)
        BC >>= 1;

    // workspace layout (u16 elements).  NOTE: Qb, Kb, Vt are contiguous —
    // the fused QKV epilogue (OUT_MODE 3) relies on Kb = Qb + 2^24 and
    // Vt = Qb + 2^25.
    u16* Pb = (u16*)d_ws;            // [BC, S, S] scores; xb aliases Pb
    u16* xb = Pb;                    // [B*S, D] x bf16 (dead after proj)
    u16* Wt = Pb + (long)BC * SS;    // 5 x [D, D]
    u16* Qb = Wt + 5L * D * D;       // [B*S, D]   (later: h)
    u16* Kb = Qb + BSD;              // [B*S, D]   (later: x_res)
    u16* Vt = Kb + BSD;              // B x [D, S]

    cvt_f32_bf16<<<dim3((unsigned)(BSD / 4 / 256)), 256, 0, stream>>>(x, xb, BSD);

    transpose5_to_bf16<<<dim3(D / 32, D / 32, 5), dim3(32, 8), 0, stream>>>(
        Wq, Wk, Wv, W1, W2, Wt, D);

    // fused QKV: [B*S, D] @ [3D, D]^T -> Qb | Kb | V^T
    g17_qkv<<<dim3(3 * D / 256, (B * S) / 256), 512, 0, stream>>>(
        xb, Wt, bq, bk, bv, Qb, D);
    // xb is dead from here; Pb may overwrite it.

    for (int c = 0; c < B; c += BC) {
        g17_qkt<<<dim3(S/256, S/256, BC), 512, 0, stream>>>(
            Qb + (long)c * SD, Kb + (long)c * SD, Pb, S, D, SD, SD, SS, 0.03125f);
        softmax_rows<<<BC * S, 256, 0, stream>>>(Pb, S);
        g17_pv<<<dim3(D/256, S/256, BC), 512, 0, stream>>>(
            Pb, Vt + (long)c * SD, x + (long)c * SD, Kb + (long)c * SD,
            D, S, SS, SD, SD, SD);
    }

    const dim3 gproj(D / 256, (B * S) / 256);    // (4, 64) = 256 blocks
    // FFN: h = relu(x_res @ W1 + b1) -> Qb;  out = 2*(h @ W2 + b2) fp32
    g17_ffn1<<<gproj, 512, 0, stream>>>(Kb, Wt + 3L*D*D, b1, Qb, D, D);
    g17_ffn2<<<gproj, 512, 0, stream>>>(Qb, Wt + 4L*D*D, b2, out, D, D, 2.0f);
}